// Round 1
// baseline (1970.011 us; speedup 1.0000x reference)
//
#include <hip/hip_runtime.h>
#include <hip/hip_bf16.h>
#include <cmath>

namespace {

constexpr int kB = 8;
constexpr int kS = 2048;
constexpr int kD = 1024;
constexpr int kN = kB * kS;          // 16384 rows
constexpr int kChunk = 128;
constexpr int kNChunk = kS / kChunk; // 16
constexpr float kEps = 1e-6f;

constexpr int TBM = 64, TBN = 64, TBK = 16;

// ---------------- decay vectors ----------------
__global__ void k_decay(float* __restrict__ decay, float* __restrict__ dbeta,
                        float* __restrict__ aL) {
  int h = blockIdx.x * blockDim.x + threadIdx.x;
  if (h >= kD) return;
  float kk = 2.0f + 6.0f * (float)h / (float)(kD - 1);
  float d = exp2f(-1.0f / kk);        // 0.5^(1/k)
  decay[h] = d;
  dbeta[h] = 1.0f - d;
  aL[h] = exp2f(-(float)kChunk / kk); // decay^CHUNK
}

// ---------------- block reduce (sum, sumsq) over 256 threads ----------------
__device__ inline void blockReduce2(float& s1, float& s2) {
#pragma unroll
  for (int off = 32; off > 0; off >>= 1) {
    s1 += __shfl_down(s1, off);
    s2 += __shfl_down(s2, off);
  }
  __shared__ float r1[4], r2[4];
  int wid = threadIdx.x >> 6;
  if ((threadIdx.x & 63) == 0) { r1[wid] = s1; r2[wid] = s2; }
  __syncthreads();
  s1 = r1[0] + r1[1] + r1[2] + r1[3];
  s2 = r2[0] + r2[1] + r2[2] + r2[3];
}

// ---------------- LayerNorm (1 block = 1 row of 1024) ----------------
__global__ __launch_bounds__(256) void k_layernorm(
    const float* __restrict__ x, const float* __restrict__ w,
    const float* __restrict__ b, float* __restrict__ y) {
  int row = blockIdx.x;
  int t = threadIdx.x;
  const float4 v = reinterpret_cast<const float4*>(x + (size_t)row * kD)[t];
  float s1 = v.x + v.y + v.z + v.w;
  float s2 = v.x * v.x + v.y * v.y + v.z * v.z + v.w * v.w;
  blockReduce2(s1, s2);
  float mu = s1 * (1.0f / kD);
  float var = s2 * (1.0f / kD) - mu * mu;
  float rs = rsqrtf(var + kEps);
  float4 wv = reinterpret_cast<const float4*>(w)[t];
  float4 bv = reinterpret_cast<const float4*>(b)[t];
  float4 o;
  o.x = (v.x - mu) * rs * wv.x + bv.x;
  o.y = (v.y - mu) * rs * wv.y + bv.y;
  o.z = (v.z - mu) * rs * wv.z + bv.z;
  o.w = (v.w - mu) * rs * wv.w + bv.w;
  reinterpret_cast<float4*>(y + (size_t)row * kD)[t] = o;
}

// ---------------- per-row mean/rstd (for LN fused into GEMM A-load) --------
__global__ __launch_bounds__(256) void k_rowstats(
    const float* __restrict__ x, float* __restrict__ stats /*[N][2]*/) {
  int row = blockIdx.x;
  int t = threadIdx.x;
  const float4 v = reinterpret_cast<const float4*>(x + (size_t)row * kD)[t];
  float s1 = v.x + v.y + v.z + v.w;
  float s2 = v.x * v.x + v.y * v.y + v.z * v.z + v.w * v.w;
  blockReduce2(s1, s2);
  if (t == 0) {
    float mu = s1 * (1.0f / kD);
    float var = s2 * (1.0f / kD) - mu * mu;
    stats[2 * row] = mu;
    stats[2 * row + 1] = rsqrtf(var + kEps);
  }
}

// ---------------- f32 tiled GEMM: C[N,1024] = A[N,K] @ W[K,1024] ----------
// A = A1 for k<1024 else A2 (concat). Optional: fused LN on A1 rows (Astats,
// Aw, Ab), per-column output scale (colscale), per-column bias.
__global__ __launch_bounds__(256) void k_gemm(
    const float* __restrict__ A1, const float* __restrict__ A2,
    const float* __restrict__ W, float* __restrict__ C, int K,
    const float* __restrict__ colscale, const float* __restrict__ bias,
    const float* __restrict__ Astats, const float* __restrict__ Aw,
    const float* __restrict__ Ab) {
  __shared__ float As[TBK][TBM + 4];
  __shared__ float Bs[TBK][TBN + 4];
  const int t = threadIdx.x;
  const int bn = blockIdx.x * TBN;
  const int bm = blockIdx.y * TBM;
  const int tx = t & 15, ty = t >> 4;
  float acc[4][4] = {};
  const int mA = t >> 2, kvA = (t & 3) * 4;   // A tile: row mA, 4 k's at kvA
  const int kRowB = t >> 4, nvB = (t & 15) * 4; // B tile: k row, 4 n's
  float muA = 0.f, rsA = 0.f;
  if (Astats) {
    muA = Astats[2 * (bm + mA)];
    rsA = Astats[2 * (bm + mA) + 1];
  }
  for (int k0 = 0; k0 < K; k0 += TBK) {
    const bool first = (k0 < kD);
    const float* Asrc = first ? A1 : A2;
    const int ks = first ? k0 : (k0 - kD);
    float4 a = *reinterpret_cast<const float4*>(
        Asrc + (size_t)(bm + mA) * kD + ks + kvA);
    if (Astats && first) {
      float4 wv = *reinterpret_cast<const float4*>(Aw + ks + kvA);
      float4 bv = *reinterpret_cast<const float4*>(Ab + ks + kvA);
      a.x = (a.x - muA) * rsA * wv.x + bv.x;
      a.y = (a.y - muA) * rsA * wv.y + bv.y;
      a.z = (a.z - muA) * rsA * wv.z + bv.z;
      a.w = (a.w - muA) * rsA * wv.w + bv.w;
    }
    float4 bq = *reinterpret_cast<const float4*>(
        W + (size_t)(k0 + kRowB) * kD + bn + nvB);
    __syncthreads();  // previous tile's compute done before LDS overwrite
    As[kvA + 0][mA] = a.x;
    As[kvA + 1][mA] = a.y;
    As[kvA + 2][mA] = a.z;
    As[kvA + 3][mA] = a.w;
    *reinterpret_cast<float4*>(&Bs[kRowB][nvB]) = bq;
    __syncthreads();
#pragma unroll
    for (int k = 0; k < TBK; ++k) {
      const float4 av = *reinterpret_cast<const float4*>(&As[k][ty * 4]);
      const float4 bv = *reinterpret_cast<const float4*>(&Bs[k][tx * 4]);
      const float aa[4] = {av.x, av.y, av.z, av.w};
      const float bb[4] = {bv.x, bv.y, bv.z, bv.w};
#pragma unroll
      for (int i = 0; i < 4; ++i)
#pragma unroll
        for (int j = 0; j < 4; ++j) acc[i][j] = fmaf(aa[i], bb[j], acc[i][j]);
    }
  }
  float cs[4], bb2[4];
#pragma unroll
  for (int j = 0; j < 4; ++j) {
    int n = bn + tx * 4 + j;
    cs[j] = colscale ? colscale[n] : 1.0f;
    bb2[j] = bias ? bias[n] : 0.0f;
  }
#pragma unroll
  for (int i = 0; i < 4; ++i) {
    float4 o;
    o.x = acc[i][0] * cs[0] + bb2[0];
    o.y = acc[i][1] * cs[1] + bb2[1];
    o.z = acc[i][2] * cs[2] + bb2[2];
    o.w = acc[i][3] * cs[3] + bb2[3];
    *reinterpret_cast<float4*>(C + (size_t)(bm + ty * 4 + i) * kD + bn +
                               tx * 4) = o;
  }
}

// ---------------- chunked scan, phase 1: per-chunk end values -------------
// thread = (b, c, h); end = sum_{i} a^{L-1-i} u[i]
__global__ __launch_bounds__(256) void k_scan_ends(
    const float* __restrict__ u, const float* __restrict__ decay,
    float* __restrict__ ends) {
  int tid = blockIdx.x * blockDim.x + threadIdx.x;  // [0, B*NCHUNK*D)
  int h = tid & (kD - 1);
  int c = (tid >> 10) & (kNChunk - 1);
  int b = tid >> 14;
  float a = decay[h];
  const float* up = u + ((size_t)(b * kS) + (size_t)c * kChunk) * kD + h;
  float v = 0.f;
#pragma unroll 8
  for (int i = 0; i < kChunk; ++i) v = fmaf(a, v, up[(size_t)i * kD]);
  ends[tid] = v;
}

// ---------------- phase 2: scan carries across chunks ---------------------
__global__ __launch_bounds__(256) void k_scan_carry(
    const float* __restrict__ ends, const float* __restrict__ aL,
    float* __restrict__ carry) {
  int tid = blockIdx.x * blockDim.x + threadIdx.x;  // [0, B*D)
  int h = tid & (kD - 1);
  int b = tid >> 10;
  float al = aL[h];
  float car = 0.f;
#pragma unroll
  for (int c = 0; c < kNChunk; ++c) {
    size_t idx = ((size_t)(b * kNChunk + c)) * kD + h;
    carry[idx] = car;
    car = fmaf(al, car, ends[idx]);
  }
}

// ---------------- phase 3: rescan with carry, in-place u -> cx ------------
__global__ __launch_bounds__(256) void k_scan_apply(
    float* __restrict__ u, const float* __restrict__ decay,
    const float* __restrict__ carry) {
  int tid = blockIdx.x * blockDim.x + threadIdx.x;
  int h = tid & (kD - 1);
  int c = (tid >> 10) & (kNChunk - 1);
  int b = tid >> 14;
  float a = decay[h];
  float v = carry[tid];
  float* up = u + ((size_t)(b * kS) + (size_t)c * kChunk) * kD + h;
#pragma unroll 8
  for (int i = 0; i < kChunk; ++i) {
    v = fmaf(a, v, up[(size_t)i * kD]);
    up[(size_t)i * kD] = v;
  }
}

// ---------------- final: LN(gpre) -> sigmoid -> blend ---------------------
__global__ __launch_bounds__(256) void k_final(
    const float* __restrict__ gpre, const float* __restrict__ res,
    const float* __restrict__ outp, const float* __restrict__ w,
    const float* __restrict__ b, float* __restrict__ y) {
  int row = blockIdx.x;
  int t = threadIdx.x;
  const float4 v = reinterpret_cast<const float4*>(gpre + (size_t)row * kD)[t];
  float s1 = v.x + v.y + v.z + v.w;
  float s2 = v.x * v.x + v.y * v.y + v.z * v.z + v.w * v.w;
  blockReduce2(s1, s2);
  float mu = s1 * (1.0f / kD);
  float var = s2 * (1.0f / kD) - mu * mu;
  float rs = rsqrtf(var + kEps);
  float4 wv = reinterpret_cast<const float4*>(w)[t];
  float4 bv = reinterpret_cast<const float4*>(b)[t];
  float4 r = reinterpret_cast<const float4*>(res + (size_t)row * kD)[t];
  float4 o = reinterpret_cast<const float4*>(outp + (size_t)row * kD)[t];
  float4 out;
  {
    float z = (v.x - mu) * rs * wv.x + bv.x;
    float g = 1.0f / (1.0f + expf(-z));
    out.x = r.x + g * (o.x - r.x);
  }
  {
    float z = (v.y - mu) * rs * wv.y + bv.y;
    float g = 1.0f / (1.0f + expf(-z));
    out.y = r.y + g * (o.y - r.y);
  }
  {
    float z = (v.z - mu) * rs * wv.z + bv.z;
    float g = 1.0f / (1.0f + expf(-z));
    out.z = r.z + g * (o.z - r.z);
  }
  {
    float z = (v.w - mu) * rs * wv.w + bv.w;
    float g = 1.0f / (1.0f + expf(-z));
    out.w = r.w + g * (o.w - r.w);
  }
  reinterpret_cast<float4*>(y + (size_t)row * kD)[t] = out;
}

}  // namespace

extern "C" void kernel_launch(void* const* d_in, const int* in_sizes, int n_in,
                              void* d_out, int out_size, void* d_ws,
                              size_t ws_size, hipStream_t stream) {
  const float* x = (const float*)d_in[0];
  const float* Wt = (const float*)d_in[1];
  const float* Wo = (const float*)d_in[2];
  const float* Wg = (const float*)d_in[3];
  const float* bg = (const float*)d_in[4];
  const float* ln1w = (const float*)d_in[5];
  const float* ln1b = (const float*)d_in[6];
  const float* lncw = (const float*)d_in[7];
  const float* lncb = (const float*)d_in[8];
  const float* lngw = (const float*)d_in[9];
  const float* lngb = (const float*)d_in[10];
  float* y = (float*)d_out;

  float* ws = (float*)d_ws;
  size_t off = 0;
  float* xn = ws + off;    off += (size_t)kN * kD;  // _x (res), 67MB
  float* u = ws + off;     off += (size_t)kN * kD;  // u -> cx -> gpre, 67MB
  float* outb = ws + off;  off += (size_t)kN * kD;  // out, 67MB
  float* decay = ws + off; off += kD;
  float* dbeta = ws + off; off += kD;
  float* aL = ws + off;    off += kD;
  float* ends = ws + off;  off += (size_t)kB * kNChunk * kD;
  float* carry = ws + off; off += (size_t)kB * kNChunk * kD;
  float* cxstats = ws + off; off += (size_t)2 * kN;

  dim3 gemmGrid(kD / TBN, kN / TBM);  // (16, 256)

  // decay vectors
  k_decay<<<(kD + 255) / 256, 256, 0, stream>>>(decay, dbeta, aL);
  // _x = LN(x)
  k_layernorm<<<kN, 256, 0, stream>>>(x, ln1w, ln1b, xn);
  // u = (_x @ Wt) * decay_beta
  k_gemm<<<gemmGrid, 256, 0, stream>>>(xn, nullptr, Wt, u, kD, dbeta, nullptr,
                                       nullptr, nullptr, nullptr);
  // chunked scan: u -> cx (in place)
  k_scan_ends<<<(kB * kNChunk * kD) / 256, 256, 0, stream>>>(u, decay, ends);
  k_scan_carry<<<(kB * kD) / 256, 256, 0, stream>>>(ends, aL, carry);
  k_scan_apply<<<(kB * kNChunk * kD) / 256, 256, 0, stream>>>(u, decay, carry);
  // per-row stats of cx (LN fused into GEMM2 A-load)
  k_rowstats<<<kN, 256, 0, stream>>>(u, cxstats);
  // out = LN(cx) @ Wo
  k_gemm<<<gemmGrid, 256, 0, stream>>>(u, nullptr, Wo, outb, kD, nullptr,
                                       nullptr, cxstats, lncw, lncb);
  // gpre = concat(_x, out) @ Wg + bg   (writes over u; cx no longer needed)
  k_gemm<<<gemmGrid, 256, 0, stream>>>(xn, outb, Wg, u, 2 * kD, nullptr, bg,
                                       nullptr, nullptr, nullptr);
  // y = (1-sigmoid(LN(gpre)))*res + sigmoid(LN(gpre))*out
  k_final<<<kN, 256, 0, stream>>>(u, xn, outb, lngw, lngb, y);
}

// Round 2
// 391.562 us; speedup vs baseline: 5.0312x; 5.0312x over previous
//
#include <hip/hip_runtime.h>
#include <hip/hip_bf16.h>
#include <cmath>
#include <cstdint>

namespace {

constexpr int kB = 8;
constexpr int kS = 2048;
constexpr int kD = 1024;
constexpr int kN = kB * kS;          // 16384 rows
constexpr int kChunk = 128;
constexpr int kNChunk = kS / kChunk; // 16
constexpr float kEps = 1e-6f;

typedef __attribute__((ext_vector_type(8))) short bf16x8;
typedef __attribute__((ext_vector_type(4))) float f32x4;

__device__ inline float bf2f(short s) {
  unsigned u = ((unsigned)(unsigned short)s) << 16;
  union { unsigned u; float f; } c;
  c.u = u;
  return c.f;
}

struct bh4 { __hip_bfloat16 a, b, c, d; };  // 8-byte bf16 quad

// async global -> LDS, 16B per lane, wave-uniform LDS base
__device__ inline void gload16(const void* g, void* l) {
  __builtin_amdgcn_global_load_lds(
      (const __attribute__((address_space(1))) void*)g,
      (__attribute__((address_space(3))) void*)l, 16, 0, 0);
}

// ---------------- decay vectors ----------------
__global__ void k_decay(float* __restrict__ decay, float* __restrict__ dbeta,
                        float* __restrict__ aL) {
  int h = blockIdx.x * blockDim.x + threadIdx.x;
  if (h >= kD) return;
  float kk = 2.0f + 6.0f * (float)h / (float)(kD - 1);
  float d = exp2f(-1.0f / kk);        // 0.5^(1/k)
  decay[h] = d;
  dbeta[h] = 1.0f - d;
  aL[h] = exp2f(-(float)kChunk / kk); // decay^CHUNK
}

// ---------------- block reduce (sum, sumsq) over 256 threads ---------------
__device__ inline void blockReduce2(float& s1, float& s2) {
#pragma unroll
  for (int off = 32; off > 0; off >>= 1) {
    s1 += __shfl_down(s1, off);
    s2 += __shfl_down(s2, off);
  }
  __shared__ float r1[4], r2[4];
  int wid = threadIdx.x >> 6;
  if ((threadIdx.x & 63) == 0) { r1[wid] = s1; r2[wid] = s2; }
  __syncthreads();
  s1 = r1[0] + r1[1] + r1[2] + r1[3];
  s2 = r2[0] + r2[1] + r2[2] + r2[3];
}

// ---------------- LayerNorm f32 -> bf16 (1 block = 1 row) -----------------
__global__ __launch_bounds__(256) void k_ln_bf16(
    const float* __restrict__ x, const float* __restrict__ w,
    const float* __restrict__ b, __hip_bfloat16* __restrict__ y) {
  int row = blockIdx.x;
  int t = threadIdx.x;
  const float4 v = reinterpret_cast<const float4*>(x + (size_t)row * kD)[t];
  float s1 = v.x + v.y + v.z + v.w;
  float s2 = v.x * v.x + v.y * v.y + v.z * v.z + v.w * v.w;
  blockReduce2(s1, s2);
  float mu = s1 * (1.0f / kD);
  float var = s2 * (1.0f / kD) - mu * mu;
  float rs = rsqrtf(var + kEps);
  float4 wv = reinterpret_cast<const float4*>(w)[t];
  float4 bv = reinterpret_cast<const float4*>(b)[t];
  bh4 o;
  o.a = __float2bfloat16((v.x - mu) * rs * wv.x + bv.x);
  o.b = __float2bfloat16((v.y - mu) * rs * wv.y + bv.y);
  o.c = __float2bfloat16((v.z - mu) * rs * wv.z + bv.z);
  o.d = __float2bfloat16((v.w - mu) * rs * wv.w + bv.w);
  reinterpret_cast<bh4*>(y + (size_t)row * kD)[t] = o;
}

// ---------------- weight transpose-cast: W[K][1024] f32 -> WT[1024][K] bf16
__global__ __launch_bounds__(256) void k_transpose_cast(
    const float* __restrict__ W, __hip_bfloat16* __restrict__ WT, int K) {
  __shared__ float tile[32][33];
  int n0 = blockIdx.x * 32, k0 = blockIdx.y * 32;
  int t = threadIdx.x;
  int tr = t >> 3, tc4 = (t & 7) * 4;
  float4 v = *reinterpret_cast<const float4*>(W + (size_t)(k0 + tr) * kD + n0 + tc4);
  tile[tc4 + 0][tr] = v.x;
  tile[tc4 + 1][tr] = v.y;
  tile[tc4 + 2][tr] = v.z;
  tile[tc4 + 3][tr] = v.w;
  __syncthreads();
  bh4 o;
  o.a = __float2bfloat16(tile[tr][tc4 + 0]);
  o.b = __float2bfloat16(tile[tr][tc4 + 1]);
  o.c = __float2bfloat16(tile[tr][tc4 + 2]);
  o.d = __float2bfloat16(tile[tr][tc4 + 3]);
  *reinterpret_cast<bh4*>(WT + (size_t)(n0 + tr) * K + k0 + tc4) = o;
}

// ---------------- bf16 MFMA GEMM (m97 structure, 128x128 tile, BK=32) -----
// C[M,1024] = A[M,K] @ BT[1024,K]^T.  A is bf16 [M][1024] (or concat of two
// such when A2 != null and k0 >= 1024).  Optional f32 out C (w/ colscale or
// bias) and/or bf16 out Cb.
__global__ __launch_bounds__(256) void k_mfma_gemm(
    const __hip_bfloat16* __restrict__ A1, const __hip_bfloat16* __restrict__ A2,
    const __hip_bfloat16* __restrict__ BT, int K,
    float* __restrict__ C, __hip_bfloat16* __restrict__ Cb,
    const float* __restrict__ colscale, const float* __restrict__ bias) {
  __shared__ short As[128 * 32];
  __shared__ short Bs[128 * 32];
  const int t = threadIdx.x;
  const int wid = t >> 6, lane = t & 63;
  const int bm = blockIdx.y * 128, bn = blockIdx.x * 128;
  const int wr = wid >> 1, wc = wid & 1;  // wave -> 64x64 quadrant
  const int r = lane & 15, kg = lane >> 4;
  const int srow = lane >> 2, scol = (lane & 3) * 8;  // staging lane map

  f32x4 acc[4][4];
#pragma unroll
  for (int m = 0; m < 4; ++m)
#pragma unroll
    for (int n = 0; n < 4; ++n) acc[m][n] = (f32x4){0.f, 0.f, 0.f, 0.f};

  for (int k0 = 0; k0 < K; k0 += 32) {
    const __hip_bfloat16* Asrc;
    int kk;
    if (A2 && k0 >= kD) { Asrc = A2; kk = k0 - kD; }
    else                { Asrc = A1; kk = k0; }
    __syncthreads();  // previous iteration's reads done before overwrite
#pragma unroll
    for (int c = 0; c < 2; ++c) {
      int chunk = c * 4 + wid;              // 0..7 -> 16 rows each
      int row = chunk * 16 + srow;
      gload16(Asrc + (size_t)(bm + row) * kD + kk + scol, As + chunk * 512);
      gload16(BT + (size_t)(bn + row) * K + k0 + scol, Bs + chunk * 512);
    }
    __syncthreads();  // staging drained (compiler emits vmcnt(0) here)
    bf16x8 af[4], bf[4];
#pragma unroll
    for (int m = 0; m < 4; ++m)
      af[m] = *reinterpret_cast<const bf16x8*>(&As[(wr * 64 + m * 16 + r) * 32 + kg * 8]);
#pragma unroll
    for (int n = 0; n < 4; ++n)
      bf[n] = *reinterpret_cast<const bf16x8*>(&Bs[(wc * 64 + n * 16 + r) * 32 + kg * 8]);
#pragma unroll
    for (int m = 0; m < 4; ++m)
#pragma unroll
      for (int n = 0; n < 4; ++n)
        acc[m][n] = __builtin_amdgcn_mfma_f32_16x16x32_bf16(af[m], bf[n], acc[m][n], 0, 0, 0);
  }

  // epilogue: D[row = kg*4+j][col = r] per fragment (m89-verified mapping)
  int col[4];
  float cs[4], bi[4];
#pragma unroll
  for (int n = 0; n < 4; ++n) {
    col[n] = bn + wc * 64 + n * 16 + r;
    cs[n] = colscale ? colscale[col[n]] : 1.0f;
    bi[n] = bias ? bias[col[n]] : 0.0f;
  }
#pragma unroll
  for (int m = 0; m < 4; ++m) {
#pragma unroll
    for (int j = 0; j < 4; ++j) {
      int row = bm + wr * 64 + m * 16 + kg * 4 + j;
#pragma unroll
      for (int n = 0; n < 4; ++n) {
        float v = acc[m][n][j] * cs[n] + bi[n];
        if (C) C[(size_t)row * kD + col[n]] = v;
        if (Cb) Cb[(size_t)row * kD + col[n]] = __float2bfloat16(v);
      }
    }
  }
}

// ---------------- chunked scan, phase 1: per-chunk end values -------------
__global__ __launch_bounds__(256) void k_scan_ends(
    const float* __restrict__ u, const float* __restrict__ decay,
    float* __restrict__ ends) {
  int tid = blockIdx.x * blockDim.x + threadIdx.x;  // [0, B*NCHUNK*D)
  int h = tid & (kD - 1);
  int c = (tid >> 10) & (kNChunk - 1);
  int b = tid >> 14;
  float a = decay[h];
  const float* up = u + ((size_t)(b * kS) + (size_t)c * kChunk) * kD + h;
  float v = 0.f;
#pragma unroll 8
  for (int i = 0; i < kChunk; ++i) v = fmaf(a, v, up[(size_t)i * kD]);
  ends[tid] = v;
}

// ---------------- phase 2: scan carries across chunks ---------------------
__global__ __launch_bounds__(256) void k_scan_carry(
    const float* __restrict__ ends, const float* __restrict__ aL,
    float* __restrict__ carry) {
  int tid = blockIdx.x * blockDim.x + threadIdx.x;  // [0, B*D)
  int h = tid & (kD - 1);
  int b = tid >> 10;
  float al = aL[h];
  float car = 0.f;
#pragma unroll
  for (int c = 0; c < kNChunk; ++c) {
    size_t idx = ((size_t)(b * kNChunk + c)) * kD + h;
    carry[idx] = car;
    car = fmaf(al, car, ends[idx]);
  }
}

// ---------------- phase 3: rescan with carry, in-place u -> cx ------------
__global__ __launch_bounds__(256) void k_scan_apply(
    float* __restrict__ u, const float* __restrict__ decay,
    const float* __restrict__ carry) {
  int tid = blockIdx.x * blockDim.x + threadIdx.x;
  int h = tid & (kD - 1);
  int c = (tid >> 10) & (kNChunk - 1);
  int b = tid >> 14;
  float a = decay[h];
  float v = carry[tid];
  float* up = u + ((size_t)(b * kS) + (size_t)c * kChunk) * kD + h;
#pragma unroll 8
  for (int i = 0; i < kChunk; ++i) {
    v = fmaf(a, v, up[(size_t)i * kD]);
    up[(size_t)i * kD] = v;
  }
}

// ---------------- final: LN(gpre) -> sigmoid -> blend ---------------------
__global__ __launch_bounds__(256) void k_final(
    const float* __restrict__ gpre, const __hip_bfloat16* __restrict__ res,
    const __hip_bfloat16* __restrict__ outp, const float* __restrict__ w,
    const float* __restrict__ b, float* __restrict__ y) {
  int row = blockIdx.x;
  int t = threadIdx.x;
  const float4 v = reinterpret_cast<const float4*>(gpre + (size_t)row * kD)[t];
  float s1 = v.x + v.y + v.z + v.w;
  float s2 = v.x * v.x + v.y * v.y + v.z * v.z + v.w * v.w;
  blockReduce2(s1, s2);
  float mu = s1 * (1.0f / kD);
  float var = s2 * (1.0f / kD) - mu * mu;
  float rs = rsqrtf(var + kEps);
  float4 wv = reinterpret_cast<const float4*>(w)[t];
  float4 bv = reinterpret_cast<const float4*>(b)[t];
  short4 r4 = reinterpret_cast<const short4*>(res + (size_t)row * kD)[t];
  short4 o4 = reinterpret_cast<const short4*>(outp + (size_t)row * kD)[t];
  float rr[4] = {bf2f(r4.x), bf2f(r4.y), bf2f(r4.z), bf2f(r4.w)};
  float oo[4] = {bf2f(o4.x), bf2f(o4.y), bf2f(o4.z), bf2f(o4.w)};
  float vv[4] = {v.x, v.y, v.z, v.w};
  float ww[4] = {wv.x, wv.y, wv.z, wv.w};
  float bb[4] = {bv.x, bv.y, bv.z, bv.w};
  float4 out;
  float* op = &out.x;
#pragma unroll
  for (int i = 0; i < 4; ++i) {
    float z = (vv[i] - mu) * rs * ww[i] + bb[i];
    float g = 1.0f / (1.0f + expf(-z));
    op[i] = rr[i] + g * (oo[i] - rr[i]);
  }
  reinterpret_cast<float4*>(y + (size_t)row * kD)[t] = out;
}

}  // namespace

extern "C" void kernel_launch(void* const* d_in, const int* in_sizes, int n_in,
                              void* d_out, int out_size, void* d_ws,
                              size_t ws_size, hipStream_t stream) {
  const float* x = (const float*)d_in[0];
  const float* Wt = (const float*)d_in[1];
  const float* Wo = (const float*)d_in[2];
  const float* Wg = (const float*)d_in[3];
  const float* bg = (const float*)d_in[4];
  const float* ln1w = (const float*)d_in[5];
  const float* ln1b = (const float*)d_in[6];
  const float* lncw = (const float*)d_in[7];
  const float* lncb = (const float*)d_in[8];
  const float* lngw = (const float*)d_in[9];
  const float* lngb = (const float*)d_in[10];
  float* y = (float*)d_out;

  char* ws = (char*)d_ws;
  size_t off = 0;
  auto alloc = [&](size_t bytes) {
    char* p = ws + off;
    off += (bytes + 255) & ~(size_t)255;
    return p;
  };
  __hip_bfloat16* xnb = (__hip_bfloat16*)alloc((size_t)kN * kD * 2);   // LN(x), res
  float* u = (float*)alloc((size_t)kN * kD * 4);                        // u -> cx -> gpre
  __hip_bfloat16* outb = (__hip_bfloat16*)alloc((size_t)kN * kD * 2);  // out
  __hip_bfloat16* cxn = (__hip_bfloat16*)alloc((size_t)kN * kD * 2);   // LN(cx)
  __hip_bfloat16* WtT = (__hip_bfloat16*)alloc((size_t)kD * kD * 2);
  __hip_bfloat16* WoT = (__hip_bfloat16*)alloc((size_t)kD * kD * 2);
  __hip_bfloat16* WgT = (__hip_bfloat16*)alloc((size_t)kD * 2 * kD * 2);
  float* decay = (float*)alloc(kD * 4);
  float* dbeta = (float*)alloc(kD * 4);
  float* aL = (float*)alloc(kD * 4);
  float* ends = (float*)alloc((size_t)kB * kNChunk * kD * 4);
  float* carry = (float*)alloc((size_t)kB * kNChunk * kD * 4);

  dim3 gemmGrid(kD / 128, kN / 128);  // (8, 128)

  k_decay<<<(kD + 255) / 256, 256, 0, stream>>>(decay, dbeta, aL);
  // weight transpose-casts (f32 [K][N] -> bf16 [N][K])
  k_transpose_cast<<<dim3(kD / 32, kD / 32), 256, 0, stream>>>(Wt, WtT, kD);
  k_transpose_cast<<<dim3(kD / 32, kD / 32), 256, 0, stream>>>(Wo, WoT, kD);
  k_transpose_cast<<<dim3(kD / 32, 2 * kD / 32), 256, 0, stream>>>(Wg, WgT, 2 * kD);
  // _x = LN(x) -> bf16
  k_ln_bf16<<<kN, 256, 0, stream>>>(x, ln1w, ln1b, xnb);
  // u = (_x @ Wt) * decay_beta   (f32 out)
  k_mfma_gemm<<<gemmGrid, 256, 0, stream>>>(xnb, nullptr, WtT, kD, u, nullptr,
                                            dbeta, nullptr);
  // chunked scan: u -> cx (in place, f32)
  k_scan_ends<<<(kB * kNChunk * kD) / 256, 256, 0, stream>>>(u, decay, ends);
  k_scan_carry<<<(kB * kD) / 256, 256, 0, stream>>>(ends, aL, carry);
  k_scan_apply<<<(kB * kNChunk * kD) / 256, 256, 0, stream>>>(u, decay, carry);
  // cxn = LN(cx) -> bf16
  k_ln_bf16<<<kN, 256, 0, stream>>>(u, lncw, lncb, cxn);
  // out = LN(cx) @ Wo  (bf16 out)
  k_mfma_gemm<<<gemmGrid, 256, 0, stream>>>(cxn, nullptr, WoT, kD, nullptr,
                                            outb, nullptr, nullptr);
  // gpre = concat(_x, out) @ Wg + bg  (f32 out, overwrites u)
  k_mfma_gemm<<<gemmGrid, 256, 0, stream>>>(xnb, outb, WgT, 2 * kD, u, nullptr,
                                            nullptr, bg);
  // y = res + sigmoid(LN(gpre)) * (out - res)
  k_final<<<kN, 256, 0, stream>>>(u, xnb, outb, lngw, lngb, y);
}

// Round 3
// 326.926 us; speedup vs baseline: 6.0259x; 1.1977x over previous
//
#include <hip/hip_runtime.h>
#include <hip/hip_bf16.h>
#include <cmath>
#include <cstdint>

namespace {

constexpr int kB = 8;
constexpr int kS = 2048;
constexpr int kD = 1024;
constexpr int kN = kB * kS;          // 16384 rows
constexpr int kChunk = 128;
constexpr int kNChunk = kS / kChunk; // 16
constexpr float kEps = 1e-6f;

typedef __attribute__((ext_vector_type(8))) short bf16x8;
typedef __attribute__((ext_vector_type(4))) float f32x4;

__device__ inline float bf2f(short s) {
  union { unsigned u; float f; } c;
  c.u = ((unsigned)(unsigned short)s) << 16;
  return c.f;
}

struct bh4 { __hip_bfloat16 a, b, c, d; };  // 8-byte bf16 quad

// async global -> LDS, 16B per lane, wave-uniform LDS base
__device__ inline void gload16(const void* g, void* l) {
  __builtin_amdgcn_global_load_lds(
      (const __attribute__((address_space(1))) void*)g,
      (__attribute__((address_space(3))) void*)l, 16, 0, 0);
}

// ---------------- decay vectors ----------------
__global__ void k_decay(float* __restrict__ decay, float* __restrict__ dbeta,
                        float* __restrict__ aL) {
  int h = blockIdx.x * blockDim.x + threadIdx.x;
  if (h >= kD) return;
  float kk = 2.0f + 6.0f * (float)h / (float)(kD - 1);
  float d = exp2f(-1.0f / kk);        // 0.5^(1/k)
  decay[h] = d;
  dbeta[h] = 1.0f - d;
  aL[h] = exp2f(-(float)kChunk / kk); // decay^CHUNK
}

// ---------------- block reduce (sum, sumsq) over 256 threads ---------------
__device__ inline void blockReduce2(float& s1, float& s2) {
#pragma unroll
  for (int off = 32; off > 0; off >>= 1) {
    s1 += __shfl_down(s1, off);
    s2 += __shfl_down(s2, off);
  }
  __shared__ float r1[4], r2[4];
  int wid = threadIdx.x >> 6;
  if ((threadIdx.x & 63) == 0) { r1[wid] = s1; r2[wid] = s2; }
  __syncthreads();
  s1 = r1[0] + r1[1] + r1[2] + r1[3];
  s2 = r2[0] + r2[1] + r2[2] + r2[3];
}

// ---------------- LayerNorm f32 -> bf16 (1 block = 1 row) -----------------
__global__ __launch_bounds__(256) void k_ln_f32in(
    const float* __restrict__ x, const float* __restrict__ w,
    const float* __restrict__ b, __hip_bfloat16* __restrict__ y) {
  int row = blockIdx.x;
  int t = threadIdx.x;
  const float4 v = reinterpret_cast<const float4*>(x + (size_t)row * kD)[t];
  float s1 = v.x + v.y + v.z + v.w;
  float s2 = v.x * v.x + v.y * v.y + v.z * v.z + v.w * v.w;
  blockReduce2(s1, s2);
  float mu = s1 * (1.0f / kD);
  float var = s2 * (1.0f / kD) - mu * mu;
  float rs = rsqrtf(var + kEps);
  float4 wv = reinterpret_cast<const float4*>(w)[t];
  float4 bv = reinterpret_cast<const float4*>(b)[t];
  bh4 o;
  o.a = __float2bfloat16((v.x - mu) * rs * wv.x + bv.x);
  o.b = __float2bfloat16((v.y - mu) * rs * wv.y + bv.y);
  o.c = __float2bfloat16((v.z - mu) * rs * wv.z + bv.z);
  o.d = __float2bfloat16((v.w - mu) * rs * wv.w + bv.w);
  reinterpret_cast<bh4*>(y + (size_t)row * kD)[t] = o;
}

// ---------------- LayerNorm bf16 -> bf16 (1 block = 1 row) ----------------
__global__ __launch_bounds__(256) void k_ln_bf16in(
    const __hip_bfloat16* __restrict__ x, const float* __restrict__ w,
    const float* __restrict__ b, __hip_bfloat16* __restrict__ y) {
  int row = blockIdx.x;
  int t = threadIdx.x;
  short4 q = reinterpret_cast<const short4*>(x + (size_t)row * kD)[t];
  float vv[4] = {bf2f(q.x), bf2f(q.y), bf2f(q.z), bf2f(q.w)};
  float s1 = vv[0] + vv[1] + vv[2] + vv[3];
  float s2 = vv[0] * vv[0] + vv[1] * vv[1] + vv[2] * vv[2] + vv[3] * vv[3];
  blockReduce2(s1, s2);
  float mu = s1 * (1.0f / kD);
  float var = s2 * (1.0f / kD) - mu * mu;
  float rs = rsqrtf(var + kEps);
  float4 wv = reinterpret_cast<const float4*>(w)[t];
  float4 bv = reinterpret_cast<const float4*>(b)[t];
  bh4 o;
  o.a = __float2bfloat16((vv[0] - mu) * rs * wv.x + bv.x);
  o.b = __float2bfloat16((vv[1] - mu) * rs * wv.y + bv.y);
  o.c = __float2bfloat16((vv[2] - mu) * rs * wv.z + bv.z);
  o.d = __float2bfloat16((vv[3] - mu) * rs * wv.w + bv.w);
  reinterpret_cast<bh4*>(y + (size_t)row * kD)[t] = o;
}

// ---------------- weight transpose-cast: W[K][1024] f32 -> WT[1024][K] bf16
__global__ __launch_bounds__(256) void k_transpose_cast(
    const float* __restrict__ W, __hip_bfloat16* __restrict__ WT, int K) {
  __shared__ float tile[32][33];
  int n0 = blockIdx.x * 32, k0 = blockIdx.y * 32;
  int t = threadIdx.x;
  int tr = t >> 3, tc4 = (t & 7) * 4;
  float4 v = *reinterpret_cast<const float4*>(W + (size_t)(k0 + tr) * kD + n0 + tc4);
  tile[tc4 + 0][tr] = v.x;
  tile[tc4 + 1][tr] = v.y;
  tile[tc4 + 2][tr] = v.z;
  tile[tc4 + 3][tr] = v.w;
  __syncthreads();
  bh4 o;
  o.a = __float2bfloat16(tile[tr][tc4 + 0]);
  o.b = __float2bfloat16(tile[tr][tc4 + 1]);
  o.c = __float2bfloat16(tile[tr][tc4 + 2]);
  o.d = __float2bfloat16(tile[tr][tc4 + 3]);
  *reinterpret_cast<bh4*>(WT + (size_t)(n0 + tr) * K + k0 + tc4) = o;
}

// ---------------- bf16 MFMA GEMM (m97 structure, 128x128 tile, BK=32) -----
// 1-D grid with bijective XCD-chunk swizzle: each XCD gets a contiguous
// bm-range for all bn -> A fetched once per disjoint slice, B hot in L2.
__global__ __launch_bounds__(256) void k_mfma_gemm(
    const __hip_bfloat16* __restrict__ A1, const __hip_bfloat16* __restrict__ A2,
    const __hip_bfloat16* __restrict__ BT, int K,
    float* __restrict__ C, __hip_bfloat16* __restrict__ Cb,
    const float* __restrict__ colscale, const float* __restrict__ bias) {
  __shared__ short As[128 * 32];
  __shared__ short Bs[128 * 32];
  const int t = threadIdx.x;
  const int wid = t >> 6, lane = t & 63;
  // XCD swizzle (nwg % 8 == 0): bid%8 = XCD -> give it a contiguous chunk
  const int nwg = gridDim.x;
  const int bid = blockIdx.x;
  const int s = (bid & 7) * (nwg >> 3) + (bid >> 3);
  const int bn = (s & 7) * 128;        // 8 column blocks (kD/128)
  const int bm = (s >> 3) * 128;
  const int wr = wid >> 1, wc = wid & 1;  // wave -> 64x64 quadrant
  const int r = lane & 15, kg = lane >> 4;
  const int srow = lane >> 2, scol = (lane & 3) * 8;  // staging lane map

  f32x4 acc[4][4];
#pragma unroll
  for (int m = 0; m < 4; ++m)
#pragma unroll
    for (int n = 0; n < 4; ++n) acc[m][n] = (f32x4){0.f, 0.f, 0.f, 0.f};

  for (int k0 = 0; k0 < K; k0 += 32) {
    const __hip_bfloat16* Asrc;
    int kk;
    if (A2 && k0 >= kD) { Asrc = A2; kk = k0 - kD; }
    else                { Asrc = A1; kk = k0; }
    __syncthreads();  // previous iteration's reads done before overwrite
#pragma unroll
    for (int c = 0; c < 2; ++c) {
      int chunk = c * 4 + wid;              // 0..7 -> 16 rows each
      int row = chunk * 16 + srow;
      gload16(Asrc + (size_t)(bm + row) * kD + kk + scol, As + chunk * 512);
      gload16(BT + (size_t)(bn + row) * K + k0 + scol, Bs + chunk * 512);
    }
    __syncthreads();  // staging drained (compiler emits vmcnt(0) here)
    bf16x8 af[4], bf[4];
#pragma unroll
    for (int m = 0; m < 4; ++m)
      af[m] = *reinterpret_cast<const bf16x8*>(&As[(wr * 64 + m * 16 + r) * 32 + kg * 8]);
#pragma unroll
    for (int n = 0; n < 4; ++n)
      bf[n] = *reinterpret_cast<const bf16x8*>(&Bs[(wc * 64 + n * 16 + r) * 32 + kg * 8]);
#pragma unroll
    for (int m = 0; m < 4; ++m)
#pragma unroll
      for (int n = 0; n < 4; ++n)
        acc[m][n] = __builtin_amdgcn_mfma_f32_16x16x32_bf16(af[m], bf[n], acc[m][n], 0, 0, 0);
  }

  // epilogue: D[row = kg*4+j][col = r] per fragment (m89-verified mapping)
  int col[4];
  float cs[4], bi[4];
#pragma unroll
  for (int n = 0; n < 4; ++n) {
    col[n] = bn + wc * 64 + n * 16 + r;
    cs[n] = colscale ? colscale[col[n]] : 1.0f;
    bi[n] = bias ? bias[col[n]] : 0.0f;
  }
#pragma unroll
  for (int m = 0; m < 4; ++m) {
#pragma unroll
    for (int j = 0; j < 4; ++j) {
      int row = bm + wr * 64 + m * 16 + kg * 4 + j;
#pragma unroll
      for (int n = 0; n < 4; ++n) {
        float v = acc[m][n][j] * cs[n] + bi[n];
        if (C) C[(size_t)row * kD + col[n]] = v;
        if (Cb) Cb[(size_t)row * kD + col[n]] = __float2bfloat16(v);
      }
    }
  }
}

// ---------------- chunked scan, phase 1: per-chunk end values (bf16 in) ---
__global__ __launch_bounds__(256) void k_scan_ends(
    const __hip_bfloat16* __restrict__ u, const float* __restrict__ decay,
    float* __restrict__ ends) {
  int tid = blockIdx.x * blockDim.x + threadIdx.x;  // [0, B*NCHUNK*D)
  int h = tid & (kD - 1);
  int c = (tid >> 10) & (kNChunk - 1);
  int b = tid >> 14;
  float a = decay[h];
  const __hip_bfloat16* up =
      u + ((size_t)(b * kS) + (size_t)c * kChunk) * kD + h;
  float v = 0.f;
#pragma unroll 8
  for (int i = 0; i < kChunk; ++i)
    v = fmaf(a, v, bf2f(*(const short*)(up + (size_t)i * kD)));
  ends[tid] = v;
}

// ---------------- phase 2: scan carries across chunks ---------------------
__global__ __launch_bounds__(256) void k_scan_carry(
    const float* __restrict__ ends, const float* __restrict__ aL,
    float* __restrict__ carry) {
  int tid = blockIdx.x * blockDim.x + threadIdx.x;  // [0, B*D)
  int h = tid & (kD - 1);
  int b = tid >> 10;
  float al = aL[h];
  float car = 0.f;
#pragma unroll
  for (int c = 0; c < kNChunk; ++c) {
    size_t idx = ((size_t)(b * kNChunk + c)) * kD + h;
    carry[idx] = car;
    car = fmaf(al, car, ends[idx]);
  }
}

// ---------------- phase 3: rescan with carry, in-place u -> cx (bf16) -----
__global__ __launch_bounds__(256) void k_scan_apply(
    __hip_bfloat16* __restrict__ u, const float* __restrict__ decay,
    const float* __restrict__ carry) {
  int tid = blockIdx.x * blockDim.x + threadIdx.x;
  int h = tid & (kD - 1);
  int c = (tid >> 10) & (kNChunk - 1);
  int b = tid >> 14;
  float a = decay[h];
  float v = carry[tid];
  __hip_bfloat16* up = u + ((size_t)(b * kS) + (size_t)c * kChunk) * kD + h;
#pragma unroll 8
  for (int i = 0; i < kChunk; ++i) {
    v = fmaf(a, v, bf2f(*(const short*)(up + (size_t)i * kD)));
    up[(size_t)i * kD] = __float2bfloat16(v);
  }
}

// ---------------- final: LN(gpre) -> sigmoid -> blend ---------------------
__global__ __launch_bounds__(256) void k_final(
    const __hip_bfloat16* __restrict__ gpre, const __hip_bfloat16* __restrict__ res,
    const __hip_bfloat16* __restrict__ outp, const float* __restrict__ w,
    const float* __restrict__ b, float* __restrict__ y) {
  int row = blockIdx.x;
  int t = threadIdx.x;
  short4 q = reinterpret_cast<const short4*>(gpre + (size_t)row * kD)[t];
  float vv[4] = {bf2f(q.x), bf2f(q.y), bf2f(q.z), bf2f(q.w)};
  float s1 = vv[0] + vv[1] + vv[2] + vv[3];
  float s2 = vv[0] * vv[0] + vv[1] * vv[1] + vv[2] * vv[2] + vv[3] * vv[3];
  blockReduce2(s1, s2);
  float mu = s1 * (1.0f / kD);
  float var = s2 * (1.0f / kD) - mu * mu;
  float rs = rsqrtf(var + kEps);
  float4 wv = reinterpret_cast<const float4*>(w)[t];
  float4 bv = reinterpret_cast<const float4*>(b)[t];
  short4 r4 = reinterpret_cast<const short4*>(res + (size_t)row * kD)[t];
  short4 o4 = reinterpret_cast<const short4*>(outp + (size_t)row * kD)[t];
  float rr[4] = {bf2f(r4.x), bf2f(r4.y), bf2f(r4.z), bf2f(r4.w)};
  float oo[4] = {bf2f(o4.x), bf2f(o4.y), bf2f(o4.z), bf2f(o4.w)};
  float ww[4] = {wv.x, wv.y, wv.z, wv.w};
  float bb[4] = {bv.x, bv.y, bv.z, bv.w};
  float4 out;
  float* op = &out.x;
#pragma unroll
  for (int i = 0; i < 4; ++i) {
    float z = (vv[i] - mu) * rs * ww[i] + bb[i];
    float g = 1.0f / (1.0f + expf(-z));
    op[i] = rr[i] + g * (oo[i] - rr[i]);
  }
  reinterpret_cast<float4*>(y + (size_t)row * kD)[t] = out;
}

}  // namespace

extern "C" void kernel_launch(void* const* d_in, const int* in_sizes, int n_in,
                              void* d_out, int out_size, void* d_ws,
                              size_t ws_size, hipStream_t stream) {
  const float* x = (const float*)d_in[0];
  const float* Wt = (const float*)d_in[1];
  const float* Wo = (const float*)d_in[2];
  const float* Wg = (const float*)d_in[3];
  const float* bg = (const float*)d_in[4];
  const float* ln1w = (const float*)d_in[5];
  const float* ln1b = (const float*)d_in[6];
  const float* lncw = (const float*)d_in[7];
  const float* lncb = (const float*)d_in[8];
  const float* lngw = (const float*)d_in[9];
  const float* lngb = (const float*)d_in[10];
  float* y = (float*)d_out;

  char* ws = (char*)d_ws;
  size_t off = 0;
  auto alloc = [&](size_t bytes) {
    char* p = ws + off;
    off += (bytes + 255) & ~(size_t)255;
    return p;
  };
  __hip_bfloat16* xnb = (__hip_bfloat16*)alloc((size_t)kN * kD * 2);  // _x (res)
  __hip_bfloat16* ub = (__hip_bfloat16*)alloc((size_t)kN * kD * 2);   // u -> cx -> gpre
  __hip_bfloat16* outb = (__hip_bfloat16*)alloc((size_t)kN * kD * 2); // out
  __hip_bfloat16* cxn = (__hip_bfloat16*)alloc((size_t)kN * kD * 2);  // LN(cx)
  __hip_bfloat16* WtT = (__hip_bfloat16*)alloc((size_t)kD * kD * 2);
  __hip_bfloat16* WoT = (__hip_bfloat16*)alloc((size_t)kD * kD * 2);
  __hip_bfloat16* WgT = (__hip_bfloat16*)alloc((size_t)kD * 2 * kD * 2);
  float* decay = (float*)alloc(kD * 4);
  float* dbeta = (float*)alloc(kD * 4);
  float* aL = (float*)alloc(kD * 4);
  float* ends = (float*)alloc((size_t)kB * kNChunk * kD * 4);
  float* carry = (float*)alloc((size_t)kB * kNChunk * kD * 4);

  const int nwg = (kD / 128) * (kN / 128);  // 8 * 128 = 1024, % 8 == 0

  k_decay<<<(kD + 255) / 256, 256, 0, stream>>>(decay, dbeta, aL);
  // weight transpose-casts (f32 [K][N] -> bf16 [N][K])
  k_transpose_cast<<<dim3(kD / 32, kD / 32), 256, 0, stream>>>(Wt, WtT, kD);
  k_transpose_cast<<<dim3(kD / 32, kD / 32), 256, 0, stream>>>(Wo, WoT, kD);
  k_transpose_cast<<<dim3(kD / 32, 2 * kD / 32), 256, 0, stream>>>(Wg, WgT, 2 * kD);
  // _x = LN(x) -> bf16
  k_ln_f32in<<<kN, 256, 0, stream>>>(x, ln1w, ln1b, xnb);
  // u = (_x @ Wt) * decay_beta   (bf16 out)
  k_mfma_gemm<<<nwg, 256, 0, stream>>>(xnb, nullptr, WtT, kD, nullptr, ub,
                                       dbeta, nullptr);
  // chunked scan: u -> cx (in place, bf16 storage, f32 accumulate)
  k_scan_ends<<<(kB * kNChunk * kD) / 256, 256, 0, stream>>>(ub, decay, ends);
  k_scan_carry<<<(kB * kD) / 256, 256, 0, stream>>>(ends, aL, carry);
  k_scan_apply<<<(kB * kNChunk * kD) / 256, 256, 0, stream>>>(ub, decay, carry);
  // cxn = LN(cx) -> bf16
  k_ln_bf16in<<<kN, 256, 0, stream>>>(ub, lncw, lncb, cxn);
  // out = LN(cx) @ Wo  (bf16 out)
  k_mfma_gemm<<<nwg, 256, 0, stream>>>(cxn, nullptr, WoT, kD, nullptr, outb,
                                       nullptr, nullptr);
  // gpre = concat(_x, out) @ Wg + bg  (bf16 out, overwrites ub; cx dead)
  k_mfma_gemm<<<nwg, 256, 0, stream>>>(xnb, outb, WgT, 2 * kD, nullptr, ub,
                                       nullptr, bg);
  // y = res + sigmoid(LN(gpre)) * (out - res)
  k_final<<<kN, 256, 0, stream>>>(ub, xnb, outb, lngw, lngb, y);
}